// Round 6
// baseline (236.987 us; speedup 1.0000x reference)
//
#include <hip/hip_runtime.h>
#include <hip/hip_bf16.h>

typedef short short8 __attribute__((ext_vector_type(8)));
typedef float floatx4 __attribute__((ext_vector_type(4)));
typedef float floatx16 __attribute__((ext_vector_type(16)));

#define DEV static __device__ __forceinline__

DEV unsigned short f2bf(float x) {
    union { float f; unsigned u; } v; v.f = x;
    unsigned r = v.u + 0x7FFFu + ((v.u >> 16) & 1u);
    return (unsigned short)(r >> 16);
}

// packed f32x2 -> bf16x2 via HIP intrinsic (compiler emits v_cvt_pk_bf16_f32)
DEV unsigned pk2(float lo, float hi) {
    union { __hip_bfloat162 h; unsigned u; } v;
    v.h = __float22bfloat162_rn(make_float2(lo, hi));
    return v.u;
}

DEV float fexp2(float x) {
#if __has_builtin(__builtin_amdgcn_exp2f)
    return __builtin_amdgcn_exp2f(x);
#else
    return exp2f(x);
#endif
}

DEV float bf2f(unsigned short s) {
    union { unsigned u; float f; } v; v.u = (unsigned)s << 16;
    return v.f;
}

// generic ptr -> LDS(as3) ptr: low 32 bits of flat LDS address are the LDS offset
DEV __attribute__((address_space(3))) unsigned int* lds_as3(void* p) {
    return (__attribute__((address_space(3))) unsigned int*)(unsigned int)(unsigned long long)p;
}
DEV const __attribute__((address_space(1))) unsigned int* gbl_as1(const void* p) {
    return (const __attribute__((address_space(1))) unsigned int*)(unsigned long long)p;
}

// ---------------------------------------------------------------------------
// f32 -> bf16 conversion of x (4096x1024), Wq/Wk/Wv (-> concat [3072][1024]), Wp
__global__ __launch_bounds__(256) void cvt_all(
    const float* __restrict__ x,  const float* __restrict__ wq,
    const float* __restrict__ wk, const float* __restrict__ wv,
    const float* __restrict__ wp,
    unsigned short* __restrict__ xb, unsigned short* __restrict__ wqkv,
    unsigned short* __restrict__ wpb)
{
    long c = (long)blockIdx.x * 256 + threadIdx.x;
    const float* src; unsigned short* dst; long off;
    if      (c <  524288) { src = x;  dst = xb;             off = c;          }
    else if (c <  655360) { src = wq; dst = wqkv;           off = c - 524288; }
    else if (c <  786432) { src = wk; dst = wqkv + 1048576; off = c - 655360; }
    else if (c <  917504) { src = wv; dst = wqkv + 2097152; off = c - 786432; }
    else                  { src = wp; dst = wpb;            off = c - 917504; }
    float4 a = ((const float4*)src)[off * 2];
    float4 b = ((const float4*)src)[off * 2 + 1];
    ushort4 r0, r1;
    r0.x = f2bf(a.x); r0.y = f2bf(a.y); r0.z = f2bf(a.z); r0.w = f2bf(a.w);
    r1.x = f2bf(b.x); r1.y = f2bf(b.y); r1.z = f2bf(b.z); r1.w = f2bf(b.w);
    ((ushort4*)dst)[off * 2]     = r0;
    ((ushort4*)dst)[off * 2 + 1] = r1;
}

// ---------------------------------------------------------------------------
// NT GEMM (m97 structure, validated round 2 incl. post-timing)
template <int EPI>
__global__ __launch_bounds__(256) void gemm_bt(
    const unsigned short* __restrict__ A, const unsigned short* __restrict__ Bw,
    int M, int N, int K,
    unsigned short* __restrict__ Qd, unsigned short* __restrict__ Kd,
    unsigned short* __restrict__ Vtd,
    float* __restrict__ Cout, const float* __restrict__ bias)
{
    __shared__ unsigned short As[128 * 32];
    __shared__ unsigned short Bs[128 * 32];
    const int t    = threadIdx.x;
    const int lane = t & 63;
    const int wv   = t >> 6;
    const int wr   = (wv >> 1) * 64, wc = (wv & 1) * 64;
    const int lr   = lane & 15,      lg = lane >> 4;
    const int m0   = blockIdx.y * 128, n0 = blockIdx.x * 128;
    const int trow = t >> 2;
    const int tk   = (t & 3) * 8;

    floatx4 acc[4][4];
#pragma unroll
    for (int i = 0; i < 4; ++i)
#pragma unroll
        for (int j = 0; j < 4; ++j)
#pragma unroll
            for (int r = 0; r < 4; ++r) acc[i][j][r] = 0.f;

    for (int k0 = 0; k0 < K; k0 += 32) {
        __syncthreads();
#pragma unroll
        for (int r = 0; r < 2; ++r) {
            const unsigned short* ga = A  + (size_t)(m0 + r * 64 + trow) * K + k0 + tk;
            const unsigned short* gb = Bw + (size_t)(n0 + r * 64 + trow) * K + k0 + tk;
            __builtin_amdgcn_global_load_lds(gbl_as1(ga), lds_as3(&As[(r * 256 + t) * 8]), 16, 0, 0);
            __builtin_amdgcn_global_load_lds(gbl_as1(gb), lds_as3(&Bs[(r * 256 + t) * 8]), 16, 0, 0);
        }
        __syncthreads();
        short8 af[4], bf[4];
#pragma unroll
        for (int i = 0; i < 4; ++i) {
            af[i] = *(const short8*)&As[(wr + i * 16 + lr) * 32 + lg * 8];
            bf[i] = *(const short8*)&Bs[(wc + i * 16 + lr) * 32 + lg * 8];
        }
#pragma unroll
        for (int i = 0; i < 4; ++i)
#pragma unroll
            for (int j = 0; j < 4; ++j)
                acc[i][j] = __builtin_amdgcn_mfma_f32_16x16x32_bf16(af[i], bf[j], acc[i][j], 0, 0, 0);
    }

    if (EPI == 1) {
#pragma unroll
        for (int j = 0; j < 4; ++j) {
            int n = n0 + wc + j * 16 + lr;
            float bv = bias[n];
#pragma unroll
            for (int i = 0; i < 4; ++i) {
                int mb = m0 + wr + i * 16 + lg * 4;
#pragma unroll
                for (int r = 0; r < 4; ++r)
                    Cout[(size_t)(mb + r) * N + n] = acc[i][j][r] + bv;
            }
        }
    } else {
        const int which = n0 >> 10;   // 0=Q 1=K 2=V
#pragma unroll
        for (int j = 0; j < 4; ++j) {
            int n = n0 + wc + j * 16 + lr;
            int h = (n & 1023) >> 6, d = n & 63;
#pragma unroll
            for (int i = 0; i < 4; ++i) {
                int mb = m0 + wr + i * 16 + lg * 4;
                int b = mb >> 11, s0 = mb & 2047;
                size_t bh = (size_t)(b * 16 + h);
                if (which == 2) {
                    ushort4 pv;
                    pv.x = f2bf(acc[i][j][0]); pv.y = f2bf(acc[i][j][1]);
                    pv.z = f2bf(acc[i][j][2]); pv.w = f2bf(acc[i][j][3]);
                    *(ushort4*)&Vtd[(bh * 64 + d) * 2048 + s0] = pv;
                } else {
                    unsigned short* dst = (which ? Kd : Qd) + (bh * 2048 + s0) * 64 + d;
#pragma unroll
                    for (int r = 0; r < 4; ++r) dst[r * 64] = f2bf(acc[i][j][r]);
                }
            }
        }
    }
}

// ---------------------------------------------------------------------------
// Causal flash attention with SPLIT-K across kernel-ordered partials.
// Grid (32 bh, 8, 3 z), 256 threads = 4 waves; wave w owns 32 q rows.
//   z=0: qt = y      (q in [0,1024)),    kv [0, qw]    -> final Ow write
//   z=1: qt = y + 8  (q in [1024,2048)), kv [0, 1024)  -> partial 0
//   z=2: qt = y + 8  (q in [1024,2048)), kv [1024, qw] -> partial 1
// Max 32 kv tiles per wave (was 64). Partials (unnormalized bf16 O + f32 m,l)
// land in the dead xb/wqkv workspace regions; attn_merge combines them.
// Inner loop body identical to round-5 validated kernel.
// Swapped QK^T: mfma(K,Q) -> lane owns q = lane&31 (col), kv in regs (rows).
// Swapped PV:   mfma(Vt,P) -> lane owns q (col), d in regs (rows).
// D layout: col = lane&31, row = (reg&3)+8*(reg>>2)+4*(lane>>5).
__global__ __launch_bounds__(256) void attn_fwd(
    const unsigned short* __restrict__ Q, const unsigned short* __restrict__ Kg,
    const unsigned short* __restrict__ Vt, unsigned short* __restrict__ O,
    unsigned short* __restrict__ Opart, float* __restrict__ MLpart)
{
    __shared__ unsigned short ot[4][32][80];   // per-wave transpose buffer (16B-aligned rows)
    const int bh = blockIdx.x;                 // b*16+h
    const int z  = blockIdx.z;
    const int qt = (z == 0) ? blockIdx.y : (8 + blockIdx.y);
    const int t  = threadIdx.x, w = t >> 6, l = t & 63;
    const int lq = l & 31, hh = l >> 5;
    const int qw = qt * 128 + w * 32;
    const int kv0beg = (z == 2) ? 1024 : 0;
    const int kvEnd  = (z == 1) ? 992  : qw;   // inclusive
    const unsigned short* Qp = Q  + (size_t)bh * 2048 * 64;
    const unsigned short* Kp = Kg + (size_t)bh * 2048 * 64;
    const unsigned short* Vp = Vt + (size_t)bh * 64 * 2048;

    const float SCALE2 = 0.18033688011112042f; // DK^-0.5 * log2(e)

    short8 qf[4];
#pragma unroll
    for (int kk = 0; kk < 4; ++kk)
        qf[kk] = *(const short8*)&Qp[(qw + lq) * 64 + kk * 16 + hh * 8];

    floatx16 o0, o1;
#pragma unroll
    for (int r = 0; r < 16; ++r) { o0[r] = 0.f; o1[r] = 0.f; }
    float mrun = -1e30f, lrun = 0.f;

    for (int kv0 = kv0beg; kv0 <= kvEnd; kv0 += 32) {
        floatx16 sa;
#pragma unroll
        for (int r = 0; r < 16; ++r) sa[r] = 0.f;
#pragma unroll
        for (int kk = 0; kk < 4; ++kk) {
            short8 kf = *(const short8*)&Kp[(kv0 + lq) * 64 + kk * 16 + hh * 8];
            sa = __builtin_amdgcn_mfma_f32_32x32x16_bf16(kf, qf[kk], sa, 0, 0, 0);
        }
        float sv[16];
        float tm = -1e30f;
        if (kv0 == qw) {           // diagonal tile: causal mask (wave-uniform; z=1 never)
#pragma unroll
            for (int r = 0; r < 16; ++r) {
                int crow = (r & 3) + 8 * (r >> 2) + 4 * hh;
                float xx = sa[r] * SCALE2;
                if (crow > lq) xx = -1e30f;
                sv[r] = xx;
                tm = fmaxf(tm, xx);
            }
        } else {
#pragma unroll
            for (int r = 0; r < 16; ++r) {
                float xx = sa[r] * SCALE2;
                sv[r] = xx;
                tm = fmaxf(tm, xx);
            }
        }
        tm = fmaxf(tm, __shfl_xor(tm, 32));
        if (!__all(tm - mrun <= 8.f)) {        // T13 defer-max (log2 domain)
            float mn = fmaxf(mrun, tm);
            float f  = fexp2(mrun - mn);
            lrun *= f;
#pragma unroll
            for (int r = 0; r < 16; ++r) { o0[r] *= f; o1[r] *= f; }
            mrun = mn;
        }
        float ps = 0.f;
#pragma unroll
        for (int r = 0; r < 16; ++r) { sv[r] = fexp2(sv[r] - mrun); ps += sv[r]; }
        ps += __shfl_xor(ps, 32);
        lrun += ps;

#pragma unroll
        for (int c = 0; c < 2; ++c) {   // kv chunks of 16
            unsigned a0 = pk2(sv[c*8+0], sv[c*8+1]);
            unsigned a1 = pk2(sv[c*8+2], sv[c*8+3]);
            unsigned b0 = pk2(sv[c*8+4], sv[c*8+5]);
            unsigned b1 = pk2(sv[c*8+6], sv[c*8+7]);
            unsigned sa0 = __shfl_xor(a0, 32), sa1 = __shfl_xor(a1, 32);
            unsigned sb0 = __shfl_xor(b0, 32), sb1 = __shfl_xor(b1, 32);
            union { unsigned u[4]; short8 v; } pf;
            pf.u[0] = hh ? sb0 : a0;
            pf.u[1] = hh ? sb1 : a1;
            pf.u[2] = hh ? b0  : sa0;
            pf.u[3] = hh ? b1  : sa1;
            short8 vf0 = *(const short8*)&Vp[(size_t)(lq)      * 2048 + kv0 + c * 16 + hh * 8];
            short8 vf1 = *(const short8*)&Vp[(size_t)(32 + lq) * 2048 + kv0 + c * 16 + hh * 8];
            o0 = __builtin_amdgcn_mfma_f32_32x32x16_bf16(vf0, pf.v, o0, 0, 0, 0);
            o1 = __builtin_amdgcn_mfma_f32_32x32x16_bf16(vf1, pf.v, o1, 0, 0, 0);
        }
    }

    if (z == 0) {
        // final: normalize, transpose via per-wave LDS, coalesced bf16 store
        float inv = 1.f / lrun;
#pragma unroll
        for (int r = 0; r < 16; ++r) {
            int crow = (r & 3) + 8 * (r >> 2) + 4 * hh;
            ot[w][lq][crow]      = f2bf(o0[r] * inv);
            ot[w][lq][32 + crow] = f2bf(o1[r] * inv);
        }
        asm volatile("s_waitcnt lgkmcnt(0)" ::: "memory");   // intra-wave LDS transpose
        const int b = bh >> 4, h = bh & 15;
        const int row = l >> 1, part = l & 1;
        size_t obase = (size_t)(b * 2048 + qw + row) * 1024 + h * 64 + part * 32;
#pragma unroll
        for (int jj = 0; jj < 4; ++jj) {
            uint4 v = *(const uint4*)&ot[w][row][part * 32 + jj * 8];
            *(uint4*)&O[obase + jj * 8] = v;
        }
    } else {
        // partial: store (m,l) f32 + unnormalized bf16 O
        const size_t sb = (size_t)((z - 1) * 32 + bh) * 1024;   // [split][bh] row base
        if (hh == 0)
            *(float2*)&MLpart[(sb + (qw - 1024) + lq) * 2] = make_float2(mrun, lrun);
#pragma unroll
        for (int r = 0; r < 16; ++r) {
            int crow = (r & 3) + 8 * (r >> 2) + 4 * hh;
            ot[w][lq][crow]      = f2bf(o0[r]);
            ot[w][lq][32 + crow] = f2bf(o1[r]);
        }
        asm volatile("s_waitcnt lgkmcnt(0)" ::: "memory");
        const int row = l >> 1, part = l & 1;
        size_t pbase = (sb + (qw - 1024) + row) * 64 + part * 32;
#pragma unroll
        for (int jj = 0; jj < 4; ++jj) {
            uint4 v = *(const uint4*)&ot[w][row][part * 32 + jj * 8];
            *(uint4*)&Opart[pbase + jj * 8] = v;
        }
    }
}

// ---------------------------------------------------------------------------
// Combine the 2 kv-split partials for q in [1024,2048) -> Ow.
// 262,144 threads: tid -> (bh[5], q'[10], d-chunk[3]).
__global__ __launch_bounds__(256) void attn_merge(
    const unsigned short* __restrict__ Opart, const float* __restrict__ MLpart,
    unsigned short* __restrict__ O)
{
    const int tid = blockIdx.x * 256 + threadIdx.x;
    const int c8  = (tid & 7) * 8;
    const int q   = (tid >> 3) & 1023;
    const int bh  = tid >> 13;
    const size_t base = (size_t)bh * 1024 + q;

    float2 ml0 = *(const float2*)&MLpart[base * 2];
    float2 ml1 = *(const float2*)&MLpart[(32768 + base) * 2];
    float M  = fmaxf(ml0.x, ml1.x);
    float w0 = fexp2(ml0.x - M), w1 = fexp2(ml1.x - M);
    float inv = 1.f / (w0 * ml0.y + w1 * ml1.y);
    w0 *= inv; w1 *= inv;

    short8 a = *(const short8*)&Opart[base * 64 + c8];
    short8 b = *(const short8*)&Opart[(size_t)2097152 + base * 64 + c8];
    float o[8];
#pragma unroll
    for (int j = 0; j < 8; ++j)
        o[j] = w0 * bf2f((unsigned short)a[j]) + w1 * bf2f((unsigned short)b[j]);
    uint4 ov;
    ov.x = pk2(o[0], o[1]); ov.y = pk2(o[2], o[3]);
    ov.z = pk2(o[4], o[5]); ov.w = pk2(o[6], o[7]);
    const int bb = bh >> 4, h = bh & 15;
    *(uint4*)&O[(size_t)(bb * 2048 + 1024 + q) * 1024 + h * 64 + c8] = ov;
}

// ---------------------------------------------------------------------------
extern "C" void kernel_launch(void* const* d_in, const int* in_sizes, int n_in,
                              void* d_out, int out_size, void* d_ws, size_t ws_size,
                              hipStream_t stream)
{
    const float* x  = (const float*)d_in[0];
    const float* Wq = (const float*)d_in[1];
    const float* Wk = (const float*)d_in[2];
    const float* Wv = (const float*)d_in[3];
    const float* Wp = (const float*)d_in[4];
    const float* bp = (const float*)d_in[5];
    float* out = (float*)d_out;

    char* ws = (char*)d_ws;
    unsigned short* xb   = (unsigned short*)(ws);              //  8.0 MiB  x bf16
    unsigned short* wqkv = (unsigned short*)(ws + 8388608);    //  6.0 MiB  [3072][1024]
    unsigned short* wpb  = (unsigned short*)(ws + 14680064);   //  2.0 MiB
    unsigned short* Qw   = (unsigned short*)(ws + 16777216);   //  [bh][s][64]
    unsigned short* Kw   = (unsigned short*)(ws + 25165824);   //  [bh][s][64]
    unsigned short* Vtw  = (unsigned short*)(ws + 33554432);   //  [bh][64][s]
    unsigned short* Ow   = (unsigned short*)(ws + 41943040);   //  [4096][1024]
    // attn partials reuse regions dead after gemm<0> (rewritten by cvt_all each launch):
    unsigned short* Opart = xb;                  // [2][32][1024][64] bf16 = 8 MiB exactly
    float*          MLp   = (float*)wqkv;        // [2][32][1024][2]  f32  = 512 KiB

    cvt_all<<<4096, 256, 0, stream>>>(x, Wq, Wk, Wv, Wp, xb, wqkv, wpb);
    gemm_bt<0><<<dim3(24, 32), 256, 0, stream>>>(xb, wqkv, 4096, 3072, 1024,
                                                 Qw, Kw, Vtw, nullptr, nullptr);
    attn_fwd<<<dim3(32, 8, 3), 256, 0, stream>>>(Qw, Kw, Vtw, Ow, Opart, MLp);
    attn_merge<<<1024, 256, 0, stream>>>(Opart, MLp, Ow);
    gemm_bt<1><<<dim3(8, 32), 256, 0, stream>>>(Ow, wpb, 4096, 1024, 1024,
                                                nullptr, nullptr, nullptr, out, bp);
}

// Round 8
// 232.701 us; speedup vs baseline: 1.0184x; 1.0184x over previous
//
#include <hip/hip_runtime.h>
#include <hip/hip_bf16.h>

typedef short short8 __attribute__((ext_vector_type(8)));
typedef float floatx4 __attribute__((ext_vector_type(4)));
typedef float floatx16 __attribute__((ext_vector_type(16)));

#define DEV static __device__ __forceinline__

DEV unsigned short f2bf(float x) {
    union { float f; unsigned u; } v; v.f = x;
    unsigned r = v.u + 0x7FFFu + ((v.u >> 16) & 1u);
    return (unsigned short)(r >> 16);
}

// packed f32x2 -> bf16x2 via HIP intrinsic (compiler emits v_cvt_pk_bf16_f32)
DEV unsigned pk2(float lo, float hi) {
    union { __hip_bfloat162 h; unsigned u; } v;
    v.h = __float22bfloat162_rn(make_float2(lo, hi));
    return v.u;
}

DEV float fexp2(float x) {
#if __has_builtin(__builtin_amdgcn_exp2f)
    return __builtin_amdgcn_exp2f(x);
#else
    return exp2f(x);
#endif
}

DEV float bf2f(unsigned short s) {
    union { unsigned u; float f; } v; v.u = (unsigned)s << 16;
    return v.f;
}

// generic ptr -> LDS(as3) ptr: low 32 bits of flat LDS address are the LDS offset
DEV __attribute__((address_space(3))) unsigned int* lds_as3(void* p) {
    return (__attribute__((address_space(3))) unsigned int*)(unsigned int)(unsigned long long)p;
}
DEV const __attribute__((address_space(1))) unsigned int* gbl_as1(const void* p) {
    return (const __attribute__((address_space(1))) unsigned int*)(unsigned long long)p;
}

// ---------------------------------------------------------------------------
// f32 -> bf16 conversion of x (4096x1024), Wq/Wk/Wv (-> concat [3072][1024]), Wp
__global__ __launch_bounds__(256) void cvt_all(
    const float* __restrict__ x,  const float* __restrict__ wq,
    const float* __restrict__ wk, const float* __restrict__ wv,
    const float* __restrict__ wp,
    unsigned short* __restrict__ xb, unsigned short* __restrict__ wqkv,
    unsigned short* __restrict__ wpb)
{
    long c = (long)blockIdx.x * 256 + threadIdx.x;
    const float* src; unsigned short* dst; long off;
    if      (c <  524288) { src = x;  dst = xb;             off = c;          }
    else if (c <  655360) { src = wq; dst = wqkv;           off = c - 524288; }
    else if (c <  786432) { src = wk; dst = wqkv + 1048576; off = c - 655360; }
    else if (c <  917504) { src = wv; dst = wqkv + 2097152; off = c - 786432; }
    else                  { src = wp; dst = wpb;            off = c - 917504; }
    float4 a = ((const float4*)src)[off * 2];
    float4 b = ((const float4*)src)[off * 2 + 1];
    ushort4 r0, r1;
    r0.x = f2bf(a.x); r0.y = f2bf(a.y); r0.z = f2bf(a.z); r0.w = f2bf(a.w);
    r1.x = f2bf(b.x); r1.y = f2bf(b.y); r1.z = f2bf(b.z); r1.w = f2bf(b.w);
    ((ushort4*)dst)[off * 2]     = r0;
    ((ushort4*)dst)[off * 2 + 1] = r1;
}

// ---------------------------------------------------------------------------
// NT GEMM (m97 structure, validated round 2 incl. post-timing)
template <int EPI>
__global__ __launch_bounds__(256) void gemm_bt(
    const unsigned short* __restrict__ A, const unsigned short* __restrict__ Bw,
    int M, int N, int K,
    unsigned short* __restrict__ Qd, unsigned short* __restrict__ Kd,
    unsigned short* __restrict__ Vtd,
    float* __restrict__ Cout, const float* __restrict__ bias)
{
    __shared__ unsigned short As[128 * 32];
    __shared__ unsigned short Bs[128 * 32];
    const int t    = threadIdx.x;
    const int lane = t & 63;
    const int wv   = t >> 6;
    const int wr   = (wv >> 1) * 64, wc = (wv & 1) * 64;
    const int lr   = lane & 15,      lg = lane >> 4;
    const int m0   = blockIdx.y * 128, n0 = blockIdx.x * 128;
    const int trow = t >> 2;
    const int tk   = (t & 3) * 8;

    floatx4 acc[4][4];
#pragma unroll
    for (int i = 0; i < 4; ++i)
#pragma unroll
        for (int j = 0; j < 4; ++j)
#pragma unroll
            for (int r = 0; r < 4; ++r) acc[i][j][r] = 0.f;

    for (int k0 = 0; k0 < K; k0 += 32) {
        __syncthreads();
#pragma unroll
        for (int r = 0; r < 2; ++r) {
            const unsigned short* ga = A  + (size_t)(m0 + r * 64 + trow) * K + k0 + tk;
            const unsigned short* gb = Bw + (size_t)(n0 + r * 64 + trow) * K + k0 + tk;
            __builtin_amdgcn_global_load_lds(gbl_as1(ga), lds_as3(&As[(r * 256 + t) * 8]), 16, 0, 0);
            __builtin_amdgcn_global_load_lds(gbl_as1(gb), lds_as3(&Bs[(r * 256 + t) * 8]), 16, 0, 0);
        }
        __syncthreads();
        short8 af[4], bf[4];
#pragma unroll
        for (int i = 0; i < 4; ++i) {
            af[i] = *(const short8*)&As[(wr + i * 16 + lr) * 32 + lg * 8];
            bf[i] = *(const short8*)&Bs[(wc + i * 16 + lr) * 32 + lg * 8];
        }
#pragma unroll
        for (int i = 0; i < 4; ++i)
#pragma unroll
            for (int j = 0; j < 4; ++j)
                acc[i][j] = __builtin_amdgcn_mfma_f32_16x16x32_bf16(af[i], bf[j], acc[i][j], 0, 0, 0);
    }

    if (EPI == 1) {
#pragma unroll
        for (int j = 0; j < 4; ++j) {
            int n = n0 + wc + j * 16 + lr;
            float bv = bias[n];
#pragma unroll
            for (int i = 0; i < 4; ++i) {
                int mb = m0 + wr + i * 16 + lg * 4;
#pragma unroll
                for (int r = 0; r < 4; ++r)
                    Cout[(size_t)(mb + r) * N + n] = acc[i][j][r] + bv;
            }
        }
    } else {
        const int which = n0 >> 10;   // 0=Q 1=K 2=V
#pragma unroll
        for (int j = 0; j < 4; ++j) {
            int n = n0 + wc + j * 16 + lr;
            int h = (n & 1023) >> 6, d = n & 63;
#pragma unroll
            for (int i = 0; i < 4; ++i) {
                int mb = m0 + wr + i * 16 + lg * 4;
                int b = mb >> 11, s0 = mb & 2047;
                size_t bh = (size_t)(b * 16 + h);
                if (which == 2) {
                    ushort4 pv;
                    pv.x = f2bf(acc[i][j][0]); pv.y = f2bf(acc[i][j][1]);
                    pv.z = f2bf(acc[i][j][2]); pv.w = f2bf(acc[i][j][3]);
                    *(ushort4*)&Vtd[(bh * 64 + d) * 2048 + s0] = pv;
                } else {
                    unsigned short* dst = (which ? Kd : Qd) + (bh * 2048 + s0) * 64 + d;
#pragma unroll
                    for (int r = 0; r < 4; ++r) dst[r * 64] = f2bf(acc[i][j][r]);
                }
            }
        }
    }
}

// ---------------------------------------------------------------------------
// Causal flash attention with SPLIT-K (round-6 validated grid/epilogues) +
// round-7 chain shortening, all wave-local:
//   * software-pipelined K/V prefetch: next tile's 8 fragment loads issue
//     right after the QK MFMAs, hide under softmax+pack+PV
//   * tree reductions for tile max / sum (depth 4 instead of 16)
//   * s_setprio(1) around MFMA clusters (T5)
// Grid (32 bh, 8, 3 z), 256 threads = 4 waves; wave w owns 32 q rows.
//   z=0: qt = y      (q in [0,1024)),    kv [0, qw]    -> final Ow write
//   z=1: qt = y + 8  (q in [1024,2048)), kv [0, 1024)  -> partial 0
//   z=2: qt = y + 8  (q in [1024,2048)), kv [1024, qw] -> partial 1
// Swapped QK^T: mfma(K,Q) -> lane owns q = lane&31 (col), kv in regs (rows).
// Swapped PV:   mfma(Vt,P) -> lane owns q (col), d in regs (rows).
// D layout: col = lane&31, row = (reg&3)+8*(reg>>2)+4*(lane>>5).
__global__ __launch_bounds__(256) void attn_fwd(
    const unsigned short* __restrict__ Q, const unsigned short* __restrict__ Kg,
    const unsigned short* __restrict__ Vt, unsigned short* __restrict__ O,
    unsigned short* __restrict__ Opart, float* __restrict__ MLpart)
{
    __shared__ unsigned short ot[4][32][80];   // per-wave transpose buffer (16B-aligned rows)
    const int bh = blockIdx.x;                 // b*16+h
    const int z  = blockIdx.z;
    const int qt = (z == 0) ? blockIdx.y : (8 + blockIdx.y);
    const int t  = threadIdx.x, w = t >> 6, l = t & 63;
    const int lq = l & 31, hh = l >> 5;
    const int qw = qt * 128 + w * 32;
    const int kv0beg = (z == 2) ? 1024 : 0;
    const int kvEnd  = (z == 1) ? 992  : qw;   // inclusive
    const unsigned short* Qp = Q  + (size_t)bh * 2048 * 64;
    const unsigned short* Kp = Kg + (size_t)bh * 2048 * 64;
    const unsigned short* Vp = Vt + (size_t)bh * 64 * 2048;

    const float SCALE2 = 0.18033688011112042f; // DK^-0.5 * log2(e)

    short8 qf[4];
#pragma unroll
    for (int kk = 0; kk < 4; ++kk)
        qf[kk] = *(const short8*)&Qp[(qw + lq) * 64 + kk * 16 + hh * 8];

    floatx16 o0, o1;
#pragma unroll
    for (int r = 0; r < 16; ++r) { o0[r] = 0.f; o1[r] = 0.f; }
    float mrun = -1e30f, lrun = 0.f;

    // prologue: load first tile's K and V fragments
    short8 kc[4], vc[4];   // vc[2c+s]: V row s*32+lq, kv chunk c
#pragma unroll
    for (int kk = 0; kk < 4; ++kk)
        kc[kk] = *(const short8*)&Kp[(kv0beg + lq) * 64 + kk * 16 + hh * 8];
#pragma unroll
    for (int c = 0; c < 2; ++c) {
        vc[c * 2]     = *(const short8*)&Vp[(size_t)(lq)      * 2048 + kv0beg + c * 16 + hh * 8];
        vc[c * 2 + 1] = *(const short8*)&Vp[(size_t)(32 + lq) * 2048 + kv0beg + c * 16 + hh * 8];
    }

    for (int kv0 = kv0beg; kv0 <= kvEnd; kv0 += 32) {
        // ---- QK^T on current K frags ----
        floatx16 sa;
#pragma unroll
        for (int r = 0; r < 16; ++r) sa[r] = 0.f;
        __builtin_amdgcn_s_setprio(1);
#pragma unroll
        for (int kk = 0; kk < 4; ++kk)
            sa = __builtin_amdgcn_mfma_f32_32x32x16_bf16(kc[kk], qf[kk], sa, 0, 0, 0);
        __builtin_amdgcn_s_setprio(0);

        // ---- prefetch next tile's K/V (clamped addr; latency hides under softmax+PV) ----
        const int kvp = (kv0 + 32 <= kvEnd) ? (kv0 + 32) : kv0beg;
        short8 kn[4], vn[4];
#pragma unroll
        for (int kk = 0; kk < 4; ++kk)
            kn[kk] = *(const short8*)&Kp[(kvp + lq) * 64 + kk * 16 + hh * 8];
#pragma unroll
        for (int c = 0; c < 2; ++c) {
            vn[c * 2]     = *(const short8*)&Vp[(size_t)(lq)      * 2048 + kvp + c * 16 + hh * 8];
            vn[c * 2 + 1] = *(const short8*)&Vp[(size_t)(32 + lq) * 2048 + kvp + c * 16 + hh * 8];
        }

        // ---- softmax (log2 domain, tree reductions) ----
        float sv[16];
        if (kv0 == qw) {           // diagonal tile: causal mask (wave-uniform; z=1 never)
#pragma unroll
            for (int r = 0; r < 16; ++r) {
                int crow = (r & 3) + 8 * (r >> 2) + 4 * hh;
                float xx = sa[r] * SCALE2;
                if (crow > lq) xx = -1e30f;
                sv[r] = xx;
            }
        } else {
#pragma unroll
            for (int r = 0; r < 16; ++r) sv[r] = sa[r] * SCALE2;
        }
        float t8[8], t4[4];
#pragma unroll
        for (int i = 0; i < 8; ++i) t8[i] = fmaxf(sv[i], sv[i + 8]);
#pragma unroll
        for (int i = 0; i < 4; ++i) t4[i] = fmaxf(t8[i], t8[i + 4]);
        float tm = fmaxf(fmaxf(t4[0], t4[1]), fmaxf(t4[2], t4[3]));
        tm = fmaxf(tm, __shfl_xor(tm, 32));
        if (!__all(tm - mrun <= 8.f)) {        // T13 defer-max (log2 domain)
            float mn = fmaxf(mrun, tm);
            float f  = fexp2(mrun - mn);
            lrun *= f;
#pragma unroll
            for (int r = 0; r < 16; ++r) { o0[r] *= f; o1[r] *= f; }
            mrun = mn;
        }
#pragma unroll
        for (int r = 0; r < 16; ++r) sv[r] = fexp2(sv[r] - mrun);
#pragma unroll
        for (int i = 0; i < 8; ++i) t8[i] = sv[i] + sv[i + 8];
#pragma unroll
        for (int i = 0; i < 4; ++i) t4[i] = t8[i] + t8[i + 4];
        float ps = (t4[0] + t4[1]) + (t4[2] + t4[3]);
        ps += __shfl_xor(ps, 32);
        lrun += ps;

        // ---- pack P to bf16 fragments + PV on current V frags ----
#pragma unroll
        for (int c = 0; c < 2; ++c) {   // kv chunks of 16
            unsigned a0 = pk2(sv[c*8+0], sv[c*8+1]);
            unsigned a1 = pk2(sv[c*8+2], sv[c*8+3]);
            unsigned b0 = pk2(sv[c*8+4], sv[c*8+5]);
            unsigned b1 = pk2(sv[c*8+6], sv[c*8+7]);
            unsigned sa0 = __shfl_xor(a0, 32), sa1 = __shfl_xor(a1, 32);
            unsigned sb0 = __shfl_xor(b0, 32), sb1 = __shfl_xor(b1, 32);
            union { unsigned u[4]; short8 v; } pf;
            pf.u[0] = hh ? sb0 : a0;
            pf.u[1] = hh ? sb1 : a1;
            pf.u[2] = hh ? b0  : sa0;
            pf.u[3] = hh ? b1  : sa1;
            __builtin_amdgcn_s_setprio(1);
            o0 = __builtin_amdgcn_mfma_f32_32x32x16_bf16(vc[c * 2],     pf.v, o0, 0, 0, 0);
            o1 = __builtin_amdgcn_mfma_f32_32x32x16_bf16(vc[c * 2 + 1], pf.v, o1, 0, 0, 0);
            __builtin_amdgcn_s_setprio(0);
        }

        // rotate prefetched frags into current
#pragma unroll
        for (int kk = 0; kk < 4; ++kk) { kc[kk] = kn[kk]; vc[kk] = vn[kk]; }
    }

    if (z == 0) {
        // final: normalize, transpose via per-wave LDS, coalesced bf16 store
        float inv = 1.f / lrun;
#pragma unroll
        for (int r = 0; r < 16; ++r) {
            int crow = (r & 3) + 8 * (r >> 2) + 4 * hh;
            ot[w][lq][crow]      = f2bf(o0[r] * inv);
            ot[w][lq][32 + crow] = f2bf(o1[r] * inv);
        }
        asm volatile("s_waitcnt lgkmcnt(0)" ::: "memory");   // intra-wave LDS transpose
        const int b = bh >> 4, h = bh & 15;
        const int row = l >> 1, part = l & 1;
        size_t obase = (size_t)(b * 2048 + qw + row) * 1024 + h * 64 + part * 32;
#pragma unroll
        for (int jj = 0; jj < 4; ++jj) {
            uint4 v = *(const uint4*)&ot[w][row][part * 32 + jj * 8];
            *(uint4*)&O[obase + jj * 8] = v;
        }
    } else {
        // partial: store (m,l) f32 + unnormalized bf16 O
        const size_t sb = (size_t)((z - 1) * 32 + bh) * 1024;   // [split][bh] row base
        if (hh == 0)
            *(float2*)&MLpart[(sb + (qw - 1024) + lq) * 2] = make_float2(mrun, lrun);
#pragma unroll
        for (int r = 0; r < 16; ++r) {
            int crow = (r & 3) + 8 * (r >> 2) + 4 * hh;
            ot[w][lq][crow]      = f2bf(o0[r]);
            ot[w][lq][32 + crow] = f2bf(o1[r]);
        }
        asm volatile("s_waitcnt lgkmcnt(0)" ::: "memory");
        const int row = l >> 1, part = l & 1;
        size_t pbase = (sb + (qw - 1024) + row) * 64 + part * 32;
#pragma unroll
        for (int jj = 0; jj < 4; ++jj) {
            uint4 v = *(const uint4*)&ot[w][row][part * 32 + jj * 8];
            *(uint4*)&Opart[pbase + jj * 8] = v;
        }
    }
}

// ---------------------------------------------------------------------------
// Combine the 2 kv-split partials for q in [1024,2048) -> Ow.
// 262,144 threads: tid -> (bh[5], q'[10], d-chunk[3]).
__global__ __launch_bounds__(256) void attn_merge(
    const unsigned short* __restrict__ Opart, const float* __restrict__ MLpart,
    unsigned short* __restrict__ O)
{
    const int tid = blockIdx.x * 256 + threadIdx.x;
    const int c8  = (tid & 7) * 8;
    const int q   = (tid >> 3) & 1023;
    const int bh  = tid >> 13;
    const size_t base = (size_t)bh * 1024 + q;

    float2 ml0 = *(const float2*)&MLpart[base * 2];
    float2 ml1 = *(const float2*)&MLpart[(32768 + base) * 2];
    float M  = fmaxf(ml0.x, ml1.x);
    float w0 = fexp2(ml0.x - M), w1 = fexp2(ml1.x - M);
    float inv = 1.f / (w0 * ml0.y + w1 * ml1.y);
    w0 *= inv; w1 *= inv;

    short8 a = *(const short8*)&Opart[base * 64 + c8];
    short8 b = *(const short8*)&Opart[(size_t)2097152 + base * 64 + c8];
    float o[8];
#pragma unroll
    for (int j = 0; j < 8; ++j)
        o[j] = w0 * bf2f((unsigned short)a[j]) + w1 * bf2f((unsigned short)b[j]);
    uint4 ov;
    ov.x = pk2(o[0], o[1]); ov.y = pk2(o[2], o[3]);
    ov.z = pk2(o[4], o[5]); ov.w = pk2(o[6], o[7]);
    const int bb = bh >> 4, h = bh & 15;
    *(uint4*)&O[(size_t)(bb * 2048 + 1024 + q) * 1024 + h * 64 + c8] = ov;
}

// ---------------------------------------------------------------------------
extern "C" void kernel_launch(void* const* d_in, const int* in_sizes, int n_in,
                              void* d_out, int out_size, void* d_ws, size_t ws_size,
                              hipStream_t stream)
{
    const float* x  = (const float*)d_in[0];
    const float* Wq = (const float*)d_in[1];
    const float* Wk = (const float*)d_in[2];
    const float* Wv = (const float*)d_in[3];
    const float* Wp = (const float*)d_in[4];
    const float* bp = (const float*)d_in[5];
    float* out = (float*)d_out;

    char* ws = (char*)d_ws;
    unsigned short* xb   = (unsigned short*)(ws);              //  8.0 MiB  x bf16
    unsigned short* wqkv = (unsigned short*)(ws + 8388608);    //  6.0 MiB  [3072][1024]
    unsigned short* wpb  = (unsigned short*)(ws + 14680064);   //  2.0 MiB
    unsigned short* Qw   = (unsigned short*)(ws + 16777216);   //  [bh][s][64]
    unsigned short* Kw   = (unsigned short*)(ws + 25165824);   //  [bh][s][64]
    unsigned short* Vtw  = (unsigned short*)(ws + 33554432);   //  [bh][64][s]
    unsigned short* Ow   = (unsigned short*)(ws + 41943040);   //  [4096][1024]
    // attn partials reuse regions dead after gemm<0> (rewritten by cvt_all each launch):
    unsigned short* Opart = xb;                  // [2][32][1024][64] bf16 = 8 MiB exactly
    float*          MLp   = (float*)wqkv;        // [2][32][1024][2]  f32  = 512 KiB

    cvt_all<<<4096, 256, 0, stream>>>(x, Wq, Wk, Wv, Wp, xb, wqkv, wpb);
    gemm_bt<0><<<dim3(24, 32), 256, 0, stream>>>(xb, wqkv, 4096, 3072, 1024,
                                                 Qw, Kw, Vtw, nullptr, nullptr);
    attn_fwd<<<dim3(32, 8, 3), 256, 0, stream>>>(Qw, Kw, Vtw, Ow, Opart, MLp);
    attn_merge<<<1024, 256, 0, stream>>>(Opart, MLp, Ow);
    gemm_bt<1><<<dim3(8, 32), 256, 0, stream>>>(Ow, wpb, 4096, 1024, 1024,
                                                nullptr, nullptr, nullptr, out, bp);
}

// Round 9
// 220.771 us; speedup vs baseline: 1.0735x; 1.0540x over previous
//
#include <hip/hip_runtime.h>
#include <hip/hip_bf16.h>

typedef short short8 __attribute__((ext_vector_type(8)));
typedef float floatx4 __attribute__((ext_vector_type(4)));
typedef float floatx16 __attribute__((ext_vector_type(16)));

#define DEV static __device__ __forceinline__

DEV unsigned short f2bf(float x) {
    union { float f; unsigned u; } v; v.f = x;
    unsigned r = v.u + 0x7FFFu + ((v.u >> 16) & 1u);
    return (unsigned short)(r >> 16);
}

// packed f32x2 -> bf16x2 via HIP intrinsic (compiler emits v_cvt_pk_bf16_f32)
DEV unsigned pk2(float lo, float hi) {
    union { __hip_bfloat162 h; unsigned u; } v;
    v.h = __float22bfloat162_rn(make_float2(lo, hi));
    return v.u;
}

DEV float fexp2(float x) {
#if __has_builtin(__builtin_amdgcn_exp2f)
    return __builtin_amdgcn_exp2f(x);
#else
    return exp2f(x);
#endif
}

DEV float bf2f(unsigned short s) {
    union { unsigned u; float f; } v; v.u = (unsigned)s << 16;
    return v.f;
}

// generic ptr -> LDS(as3) ptr: low 32 bits of flat LDS address are the LDS offset
DEV __attribute__((address_space(3))) unsigned int* lds_as3(void* p) {
    return (__attribute__((address_space(3))) unsigned int*)(unsigned int)(unsigned long long)p;
}
DEV const __attribute__((address_space(1))) unsigned int* gbl_as1(const void* p) {
    return (const __attribute__((address_space(1))) unsigned int*)(unsigned long long)p;
}

// ---------------------------------------------------------------------------
// f32 -> bf16 conversion of x (4096x1024), Wq/Wk/Wv (-> concat [3072][1024]), Wp
__global__ __launch_bounds__(256) void cvt_all(
    const float* __restrict__ x,  const float* __restrict__ wq,
    const float* __restrict__ wk, const float* __restrict__ wv,
    const float* __restrict__ wp,
    unsigned short* __restrict__ xb, unsigned short* __restrict__ wqkv,
    unsigned short* __restrict__ wpb)
{
    long c = (long)blockIdx.x * 256 + threadIdx.x;
    const float* src; unsigned short* dst; long off;
    if      (c <  524288) { src = x;  dst = xb;             off = c;          }
    else if (c <  655360) { src = wq; dst = wqkv;           off = c - 524288; }
    else if (c <  786432) { src = wk; dst = wqkv + 1048576; off = c - 655360; }
    else if (c <  917504) { src = wv; dst = wqkv + 2097152; off = c - 786432; }
    else                  { src = wp; dst = wpb;            off = c - 917504; }
    float4 a = ((const float4*)src)[off * 2];
    float4 b = ((const float4*)src)[off * 2 + 1];
    ushort4 r0, r1;
    r0.x = f2bf(a.x); r0.y = f2bf(a.y); r0.z = f2bf(a.z); r0.w = f2bf(a.w);
    r1.x = f2bf(b.x); r1.y = f2bf(b.y); r1.z = f2bf(b.z); r1.w = f2bf(b.w);
    ((ushort4*)dst)[off * 2]     = r0;
    ((ushort4*)dst)[off * 2 + 1] = r1;
}

// ---------------------------------------------------------------------------
// NT GEMM (m97 structure, validated round 2 incl. post-timing)
template <int EPI>
__global__ __launch_bounds__(256) void gemm_bt(
    const unsigned short* __restrict__ A, const unsigned short* __restrict__ Bw,
    int M, int N, int K,
    unsigned short* __restrict__ Qd, unsigned short* __restrict__ Kd,
    unsigned short* __restrict__ Vtd,
    float* __restrict__ Cout, const float* __restrict__ bias)
{
    __shared__ unsigned short As[128 * 32];
    __shared__ unsigned short Bs[128 * 32];
    const int t    = threadIdx.x;
    const int lane = t & 63;
    const int wv   = t >> 6;
    const int wr   = (wv >> 1) * 64, wc = (wv & 1) * 64;
    const int lr   = lane & 15,      lg = lane >> 4;
    const int m0   = blockIdx.y * 128, n0 = blockIdx.x * 128;
    const int trow = t >> 2;
    const int tk   = (t & 3) * 8;

    floatx4 acc[4][4];
#pragma unroll
    for (int i = 0; i < 4; ++i)
#pragma unroll
        for (int j = 0; j < 4; ++j)
#pragma unroll
            for (int r = 0; r < 4; ++r) acc[i][j][r] = 0.f;

    for (int k0 = 0; k0 < K; k0 += 32) {
        __syncthreads();
#pragma unroll
        for (int r = 0; r < 2; ++r) {
            const unsigned short* ga = A  + (size_t)(m0 + r * 64 + trow) * K + k0 + tk;
            const unsigned short* gb = Bw + (size_t)(n0 + r * 64 + trow) * K + k0 + tk;
            __builtin_amdgcn_global_load_lds(gbl_as1(ga), lds_as3(&As[(r * 256 + t) * 8]), 16, 0, 0);
            __builtin_amdgcn_global_load_lds(gbl_as1(gb), lds_as3(&Bs[(r * 256 + t) * 8]), 16, 0, 0);
        }
        __syncthreads();
        short8 af[4], bf[4];
#pragma unroll
        for (int i = 0; i < 4; ++i) {
            af[i] = *(const short8*)&As[(wr + i * 16 + lr) * 32 + lg * 8];
            bf[i] = *(const short8*)&Bs[(wc + i * 16 + lr) * 32 + lg * 8];
        }
#pragma unroll
        for (int i = 0; i < 4; ++i)
#pragma unroll
            for (int j = 0; j < 4; ++j)
                acc[i][j] = __builtin_amdgcn_mfma_f32_16x16x32_bf16(af[i], bf[j], acc[i][j], 0, 0, 0);
    }

    if (EPI == 1) {
#pragma unroll
        for (int j = 0; j < 4; ++j) {
            int n = n0 + wc + j * 16 + lr;
            float bv = bias[n];
#pragma unroll
            for (int i = 0; i < 4; ++i) {
                int mb = m0 + wr + i * 16 + lg * 4;
#pragma unroll
                for (int r = 0; r < 4; ++r)
                    Cout[(size_t)(mb + r) * N + n] = acc[i][j][r] + bv;
            }
        }
    } else {
        const int which = n0 >> 10;   // 0=Q 1=K 2=V
#pragma unroll
        for (int j = 0; j < 4; ++j) {
            int n = n0 + wc + j * 16 + lr;
            int h = (n & 1023) >> 6, d = n & 63;
#pragma unroll
            for (int i = 0; i < 4; ++i) {
                int mb = m0 + wr + i * 16 + lg * 4;
                int b = mb >> 11, s0 = mb & 2047;
                size_t bh = (size_t)(b * 16 + h);
                if (which == 2) {
                    ushort4 pv;
                    pv.x = f2bf(acc[i][j][0]); pv.y = f2bf(acc[i][j][1]);
                    pv.z = f2bf(acc[i][j][2]); pv.w = f2bf(acc[i][j][3]);
                    *(ushort4*)&Vtd[(bh * 64 + d) * 2048 + s0] = pv;
                } else {
                    unsigned short* dst = (which ? Kd : Qd) + (bh * 2048 + s0) * 64 + d;
#pragma unroll
                    for (int r = 0; r < 4; ++r) dst[r * 64] = f2bf(acc[i][j][r]);
                }
            }
        }
    }
}

// ---------------------------------------------------------------------------
// Causal flash attention with SPLIT-K + per-CU work balancing.
// Grid (32 bh, 8, 3 z), 256 threads = 4 waves; wave w owns 32 q rows.
// Blocks linearize x-fastest; block->CU assignment is (approx) modular, so a
// CU gets the SAME y for all three z. Work: z0/z2 blocks = 16y+10 tile-iters,
// z1 = 128. Flipping y within z=2 (ye = 7-y) makes every CU's sum constant:
// (16y+10) + 128 + (16(7-y)+10) = 260  -> balanced makespan.
//   z=0: qt = ye     (q in [0,1024)),    kv [0, qw]    -> final Ow write
//   z=1: qt = 8 + ye (q in [1024,2048)), kv [0, 1024)  -> partial 0
//   z=2: qt = 8 + ye (q in [1024,2048)), kv [1024, qw] -> partial 1
// Inner loop: round-7/8 validated (prefetch, tree reductions, setprio).
// Swapped QK^T: mfma(K,Q) -> lane owns q = lane&31 (col), kv in regs (rows).
// Swapped PV:   mfma(Vt,P) -> lane owns q (col), d in regs (rows).
// D layout: col = lane&31, row = (reg&3)+8*(reg>>2)+4*(lane>>5).
__global__ __launch_bounds__(256) void attn_fwd(
    const unsigned short* __restrict__ Q, const unsigned short* __restrict__ Kg,
    const unsigned short* __restrict__ Vt, unsigned short* __restrict__ O,
    unsigned short* __restrict__ Opart, float* __restrict__ MLpart)
{
    __shared__ unsigned short ot[4][32][80];   // per-wave transpose buffer (16B-aligned rows)
    const int bh = blockIdx.x;                 // b*16+h
    const int z  = blockIdx.z;
    const int ye = (z == 2) ? (7 - (int)blockIdx.y) : (int)blockIdx.y;  // per-CU balance
    const int qt = (z == 0) ? ye : (8 + ye);
    const int t  = threadIdx.x, w = t >> 6, l = t & 63;
    const int lq = l & 31, hh = l >> 5;
    const int qw = qt * 128 + w * 32;
    const int kv0beg = (z == 2) ? 1024 : 0;
    const int kvEnd  = (z == 1) ? 992  : qw;   // inclusive
    const unsigned short* Qp = Q  + (size_t)bh * 2048 * 64;
    const unsigned short* Kp = Kg + (size_t)bh * 2048 * 64;
    const unsigned short* Vp = Vt + (size_t)bh * 64 * 2048;

    const float SCALE2 = 0.18033688011112042f; // DK^-0.5 * log2(e)

    short8 qf[4];
#pragma unroll
    for (int kk = 0; kk < 4; ++kk)
        qf[kk] = *(const short8*)&Qp[(qw + lq) * 64 + kk * 16 + hh * 8];

    floatx16 o0, o1;
#pragma unroll
    for (int r = 0; r < 16; ++r) { o0[r] = 0.f; o1[r] = 0.f; }
    float mrun = -1e30f, lrun = 0.f;

    // prologue: load first tile's K and V fragments
    short8 kc[4], vc[4];   // vc[2c+s]: V row s*32+lq, kv chunk c
#pragma unroll
    for (int kk = 0; kk < 4; ++kk)
        kc[kk] = *(const short8*)&Kp[(kv0beg + lq) * 64 + kk * 16 + hh * 8];
#pragma unroll
    for (int c = 0; c < 2; ++c) {
        vc[c * 2]     = *(const short8*)&Vp[(size_t)(lq)      * 2048 + kv0beg + c * 16 + hh * 8];
        vc[c * 2 + 1] = *(const short8*)&Vp[(size_t)(32 + lq) * 2048 + kv0beg + c * 16 + hh * 8];
    }

    for (int kv0 = kv0beg; kv0 <= kvEnd; kv0 += 32) {
        // ---- QK^T on current K frags ----
        floatx16 sa;
#pragma unroll
        for (int r = 0; r < 16; ++r) sa[r] = 0.f;
        __builtin_amdgcn_s_setprio(1);
#pragma unroll
        for (int kk = 0; kk < 4; ++kk)
            sa = __builtin_amdgcn_mfma_f32_32x32x16_bf16(kc[kk], qf[kk], sa, 0, 0, 0);
        __builtin_amdgcn_s_setprio(0);

        // ---- prefetch next tile's K/V (clamped addr; latency hides under softmax+PV) ----
        const int kvp = (kv0 + 32 <= kvEnd) ? (kv0 + 32) : kv0beg;
        short8 kn[4], vn[4];
#pragma unroll
        for (int kk = 0; kk < 4; ++kk)
            kn[kk] = *(const short8*)&Kp[(kvp + lq) * 64 + kk * 16 + hh * 8];
#pragma unroll
        for (int c = 0; c < 2; ++c) {
            vn[c * 2]     = *(const short8*)&Vp[(size_t)(lq)      * 2048 + kvp + c * 16 + hh * 8];
            vn[c * 2 + 1] = *(const short8*)&Vp[(size_t)(32 + lq) * 2048 + kvp + c * 16 + hh * 8];
        }

        // ---- softmax (log2 domain, tree reductions) ----
        float sv[16];
        if (kv0 == qw) {           // diagonal tile: causal mask (wave-uniform; z=1 never)
#pragma unroll
            for (int r = 0; r < 16; ++r) {
                int crow = (r & 3) + 8 * (r >> 2) + 4 * hh;
                float xx = sa[r] * SCALE2;
                if (crow > lq) xx = -1e30f;
                sv[r] = xx;
            }
        } else {
#pragma unroll
            for (int r = 0; r < 16; ++r) sv[r] = sa[r] * SCALE2;
        }
        float t8[8], t4[4];
#pragma unroll
        for (int i = 0; i < 8; ++i) t8[i] = fmaxf(sv[i], sv[i + 8]);
#pragma unroll
        for (int i = 0; i < 4; ++i) t4[i] = fmaxf(t8[i], t8[i + 4]);
        float tm = fmaxf(fmaxf(t4[0], t4[1]), fmaxf(t4[2], t4[3]));
        tm = fmaxf(tm, __shfl_xor(tm, 32));
        if (!__all(tm - mrun <= 8.f)) {        // T13 defer-max (log2 domain)
            float mn = fmaxf(mrun, tm);
            float f  = fexp2(mrun - mn);
            lrun *= f;
#pragma unroll
            for (int r = 0; r < 16; ++r) { o0[r] *= f; o1[r] *= f; }
            mrun = mn;
        }
#pragma unroll
        for (int r = 0; r < 16; ++r) sv[r] = fexp2(sv[r] - mrun);
#pragma unroll
        for (int i = 0; i < 8; ++i) t8[i] = sv[i] + sv[i + 8];
#pragma unroll
        for (int i = 0; i < 4; ++i) t4[i] = t8[i] + t8[i + 4];
        float ps = (t4[0] + t4[1]) + (t4[2] + t4[3]);
        ps += __shfl_xor(ps, 32);
        lrun += ps;

        // ---- pack P to bf16 fragments + PV on current V frags ----
#pragma unroll
        for (int c = 0; c < 2; ++c) {   // kv chunks of 16
            unsigned a0 = pk2(sv[c*8+0], sv[c*8+1]);
            unsigned a1 = pk2(sv[c*8+2], sv[c*8+3]);
            unsigned b0 = pk2(sv[c*8+4], sv[c*8+5]);
            unsigned b1 = pk2(sv[c*8+6], sv[c*8+7]);
            unsigned sa0 = __shfl_xor(a0, 32), sa1 = __shfl_xor(a1, 32);
            unsigned sb0 = __shfl_xor(b0, 32), sb1 = __shfl_xor(b1, 32);
            union { unsigned u[4]; short8 v; } pf;
            pf.u[0] = hh ? sb0 : a0;
            pf.u[1] = hh ? sb1 : a1;
            pf.u[2] = hh ? b0  : sa0;
            pf.u[3] = hh ? b1  : sa1;
            __builtin_amdgcn_s_setprio(1);
            o0 = __builtin_amdgcn_mfma_f32_32x32x16_bf16(vc[c * 2],     pf.v, o0, 0, 0, 0);
            o1 = __builtin_amdgcn_mfma_f32_32x32x16_bf16(vc[c * 2 + 1], pf.v, o1, 0, 0, 0);
            __builtin_amdgcn_s_setprio(0);
        }

        // rotate prefetched frags into current
#pragma unroll
        for (int kk = 0; kk < 4; ++kk) { kc[kk] = kn[kk]; vc[kk] = vn[kk]; }
    }

    if (z == 0) {
        // final: normalize, transpose via per-wave LDS, coalesced bf16 store
        float inv = 1.f / lrun;
#pragma unroll
        for (int r = 0; r < 16; ++r) {
            int crow = (r & 3) + 8 * (r >> 2) + 4 * hh;
            ot[w][lq][crow]      = f2bf(o0[r] * inv);
            ot[w][lq][32 + crow] = f2bf(o1[r] * inv);
        }
        asm volatile("s_waitcnt lgkmcnt(0)" ::: "memory");   // intra-wave LDS transpose
        const int b = bh >> 4, h = bh & 15;
        const int row = l >> 1, part = l & 1;
        size_t obase = (size_t)(b * 2048 + qw + row) * 1024 + h * 64 + part * 32;
#pragma unroll
        for (int jj = 0; jj < 4; ++jj) {
            uint4 v = *(const uint4*)&ot[w][row][part * 32 + jj * 8];
            *(uint4*)&O[obase + jj * 8] = v;
        }
    } else {
        // partial: store (m,l) f32 + unnormalized bf16 O
        const size_t sb = (size_t)((z - 1) * 32 + bh) * 1024;   // [split][bh] row base
        if (hh == 0)
            *(float2*)&MLpart[(sb + (qw - 1024) + lq) * 2] = make_float2(mrun, lrun);
#pragma unroll
        for (int r = 0; r < 16; ++r) {
            int crow = (r & 3) + 8 * (r >> 2) + 4 * hh;
            ot[w][lq][crow]      = f2bf(o0[r]);
            ot[w][lq][32 + crow] = f2bf(o1[r]);
        }
        asm volatile("s_waitcnt lgkmcnt(0)" ::: "memory");
        const int row = l >> 1, part = l & 1;
        size_t pbase = (sb + (qw - 1024) + row) * 64 + part * 32;
#pragma unroll
        for (int jj = 0; jj < 4; ++jj) {
            uint4 v = *(const uint4*)&ot[w][row][part * 32 + jj * 8];
            *(uint4*)&Opart[pbase + jj * 8] = v;
        }
    }
}

// ---------------------------------------------------------------------------
// Combine the 2 kv-split partials for q in [1024,2048) -> Ow.
// 262,144 threads: tid -> (bh[5], q'[10], d-chunk[3]).
__global__ __launch_bounds__(256) void attn_merge(
    const unsigned short* __restrict__ Opart, const float* __restrict__ MLpart,
    unsigned short* __restrict__ O)
{
    const int tid = blockIdx.x * 256 + threadIdx.x;
    const int c8  = (tid & 7) * 8;
    const int q   = (tid >> 3) & 1023;
    const int bh  = tid >> 13;
    const size_t base = (size_t)bh * 1024 + q;

    float2 ml0 = *(const float2*)&MLpart[base * 2];
    float2 ml1 = *(const float2*)&MLpart[(32768 + base) * 2];
    float M  = fmaxf(ml0.x, ml1.x);
    float w0 = fexp2(ml0.x - M), w1 = fexp2(ml1.x - M);
    float inv = 1.f / (w0 * ml0.y + w1 * ml1.y);
    w0 *= inv; w1 *= inv;

    short8 a = *(const short8*)&Opart[base * 64 + c8];
    short8 b = *(const short8*)&Opart[(size_t)2097152 + base * 64 + c8];
    float o[8];
#pragma unroll
    for (int j = 0; j < 8; ++j)
        o[j] = w0 * bf2f((unsigned short)a[j]) + w1 * bf2f((unsigned short)b[j]);
    uint4 ov;
    ov.x = pk2(o[0], o[1]); ov.y = pk2(o[2], o[3]);
    ov.z = pk2(o[4], o[5]); ov.w = pk2(o[6], o[7]);
    const int bb = bh >> 4, h = bh & 15;
    *(uint4*)&O[(size_t)(bb * 2048 + 1024 + q) * 1024 + h * 64 + c8] = ov;
}

// ---------------------------------------------------------------------------
extern "C" void kernel_launch(void* const* d_in, const int* in_sizes, int n_in,
                              void* d_out, int out_size, void* d_ws, size_t ws_size,
                              hipStream_t stream)
{
    const float* x  = (const float*)d_in[0];
    const float* Wq = (const float*)d_in[1];
    const float* Wk = (const float*)d_in[2];
    const float* Wv = (const float*)d_in[3];
    const float* Wp = (const float*)d_in[4];
    const float* bp = (const float*)d_in[5];
    float* out = (float*)d_out;

    char* ws = (char*)d_ws;
    unsigned short* xb   = (unsigned short*)(ws);              //  8.0 MiB  x bf16
    unsigned short* wqkv = (unsigned short*)(ws + 8388608);    //  6.0 MiB  [3072][1024]
    unsigned short* wpb  = (unsigned short*)(ws + 14680064);   //  2.0 MiB
    unsigned short* Qw   = (unsigned short*)(ws + 16777216);   //  [bh][s][64]
    unsigned short* Kw   = (unsigned short*)(ws + 25165824);   //  [bh][s][64]
    unsigned short* Vtw  = (unsigned short*)(ws + 33554432);   //  [bh][64][s]
    unsigned short* Ow   = (unsigned short*)(ws + 41943040);   //  [4096][1024]
    // attn partials reuse regions dead after gemm<0> (rewritten by cvt_all each launch):
    unsigned short* Opart = xb;                  // [2][32][1024][64] bf16 = 8 MiB exactly
    float*          MLp   = (float*)wqkv;        // [2][32][1024][2]  f32  = 512 KiB

    cvt_all<<<4096, 256, 0, stream>>>(x, Wq, Wk, Wv, Wp, xb, wqkv, wpb);
    gemm_bt<0><<<dim3(24, 32), 256, 0, stream>>>(xb, wqkv, 4096, 3072, 1024,
                                                 Qw, Kw, Vtw, nullptr, nullptr);
    attn_fwd<<<dim3(32, 8, 3), 256, 0, stream>>>(Qw, Kw, Vtw, Ow, Opart, MLp);
    attn_merge<<<1024, 256, 0, stream>>>(Opart, MLp, Ow);
    gemm_bt<1><<<dim3(8, 32), 256, 0, stream>>>(Ow, wpb, 4096, 1024, 1024,
                                                nullptr, nullptr, nullptr, out, bp);
}